// Round 1
// baseline (1882.202 us; speedup 1.0000x reference)
//
#include <hip/hip_runtime.h>
#include <math.h>

// GraphSAGE-mean 2-layer: feat[200000,26], 6.4M edges, W1: 26->40 (relu), W2: 40->24, log_softmax.
// Layer-2 trick: aggregate h1@W2_neigh (24 dims) instead of h1 (40 dims) — mean commutes with linear.

__global__ void degree_kernel(const int* __restrict__ dst, float* __restrict__ deg, int n_edges) {
    int e = blockIdx.x * blockDim.x + threadIdx.x;
    if (e < n_edges) atomicAdd(&deg[dst[e]], 1.0f);
}

// 32 lanes per edge, lanes [0,F) active. Coalesced gather of x[src] and coalesced atomics into out[dst].
template<int F>
__global__ void scatter_add_kernel(const float* __restrict__ x, const int* __restrict__ src,
                                   const int* __restrict__ dst, float* __restrict__ out,
                                   int n_edges) {
    long long tid = (long long)blockIdx.x * blockDim.x + threadIdx.x;
    int e = (int)(tid >> 5);
    if (e >= n_edges) return;
    int f = (int)(tid & 31);
    if (f >= F) return;
    int s = src[e];
    int d = dst[e];
    atomicAdd(&out[(long long)d * F + f], x[(long long)s * F + f]);
}

// Per-node fused: h1 = relu(feat@W1s + (agg1*dinv)@W1n + b1);
// outp = h1@W2s + b2 (self term of layer 2, into d_out); t2 = h1@W2n (to be aggregated).
__global__ void __launch_bounds__(256) node_mlp_kernel(
        const float* __restrict__ feat, const float* __restrict__ agg1,
        const float* __restrict__ deg,
        const float* __restrict__ W1s, const float* __restrict__ W1n, const float* __restrict__ b1,
        const float* __restrict__ W2s, const float* __restrict__ W2n, const float* __restrict__ b2,
        float* __restrict__ outp, float* __restrict__ t2, int n_nodes) {
    __shared__ float sW1s[26 * 40];
    __shared__ float sW1n[26 * 40];
    __shared__ float sW2s[40 * 24];
    __shared__ float sW2n[40 * 24];
    __shared__ float sb1[40];
    __shared__ float sb2[24];
    int t = threadIdx.x;
    for (int i = t; i < 26 * 40; i += 256) { sW1s[i] = W1s[i]; sW1n[i] = W1n[i]; }
    for (int i = t; i < 40 * 24; i += 256) { sW2s[i] = W2s[i]; sW2n[i] = W2n[i]; }
    if (t < 40) sb1[t] = b1[t];
    if (t < 24) sb2[t] = b2[t];
    __syncthreads();

    int n = blockIdx.x * 256 + t;
    if (n >= n_nodes) return;

    float d = deg[n];
    float dinv = d > 0.0f ? 1.0f / d : 0.0f;

    float h[40];
#pragma unroll
    for (int j = 0; j < 40; j++) h[j] = sb1[j];

    const float* fr = feat + (long long)n * 26;
    const float* ar = agg1 + (long long)n * 26;
#pragma unroll
    for (int k = 0; k < 26; k++) {
        float f = fr[k];
        float a = ar[k] * dinv;
#pragma unroll
        for (int j = 0; j < 40; j++) h[j] += f * sW1s[k * 40 + j] + a * sW1n[k * 40 + j];
    }
#pragma unroll
    for (int j = 0; j < 40; j++) h[j] = h[j] > 0.0f ? h[j] : 0.0f;

    float o[24], tt[24];
#pragma unroll
    for (int j = 0; j < 24; j++) { o[j] = sb2[j]; tt[j] = 0.0f; }
#pragma unroll
    for (int k = 0; k < 40; k++) {
        float hv = h[k];
#pragma unroll
        for (int j = 0; j < 24; j++) {
            o[j]  += hv * sW2s[k * 24 + j];
            tt[j] += hv * sW2n[k * 24 + j];
        }
    }
    float* op = outp + (long long)n * 24;
    float* tp = t2   + (long long)n * 24;
#pragma unroll
    for (int j = 0; j < 24; j++) { op[j] = o[j]; tp[j] = tt[j]; }
}

// d_out += aggT*dinv, then log_softmax over the 24 classes.
__global__ void __launch_bounds__(256) finalize_kernel(
        float* __restrict__ outp, const float* __restrict__ aggT,
        const float* __restrict__ deg, int n_nodes) {
    int n = blockIdx.x * 256 + threadIdx.x;
    if (n >= n_nodes) return;
    float d = deg[n];
    float dinv = d > 0.0f ? 1.0f / d : 0.0f;
    float v[24];
    float m = -3.4e38f;
    float* op = outp + (long long)n * 24;
    const float* ap = aggT + (long long)n * 24;
#pragma unroll
    for (int j = 0; j < 24; j++) {
        v[j] = op[j] + ap[j] * dinv;
        m = fmaxf(m, v[j]);
    }
    float s = 0.0f;
#pragma unroll
    for (int j = 0; j < 24; j++) s += expf(v[j] - m);
    float l = m + logf(s);
#pragma unroll
    for (int j = 0; j < 24; j++) op[j] = v[j] - l;
}

extern "C" void kernel_launch(void* const* d_in, const int* in_sizes, int n_in,
                              void* d_out, int out_size, void* d_ws, size_t ws_size,
                              hipStream_t stream) {
    const float* feat = (const float*)d_in[0];
    const int*   src  = (const int*)d_in[1];
    const int*   dst  = (const int*)d_in[2];
    const float* W1s  = (const float*)d_in[3];
    const float* W1n  = (const float*)d_in[4];
    const float* b1   = (const float*)d_in[5];
    const float* W2s  = (const float*)d_in[6];
    const float* W2n  = (const float*)d_in[7];
    const float* b2   = (const float*)d_in[8];

    int n_nodes = in_sizes[0] / 26;
    int n_edges = in_sizes[1];
    float* out = (float*)d_out;

    // Workspace layout: deg[N] | agg1[N*26] | t2[N*24] | aggT[N*24]  (~60 MB)
    float* deg  = (float*)d_ws;
    float* agg1 = deg + n_nodes;
    float* t2   = agg1 + (size_t)n_nodes * 26;
    float* aggT = t2 + (size_t)n_nodes * 24;

    hipMemsetAsync(deg,  0, sizeof(float) * (size_t)n_nodes, stream);
    hipMemsetAsync(agg1, 0, sizeof(float) * (size_t)n_nodes * 26, stream);
    hipMemsetAsync(aggT, 0, sizeof(float) * (size_t)n_nodes * 24, stream);

    degree_kernel<<<(n_edges + 255) / 256, 256, 0, stream>>>(dst, deg, n_edges);

    {
        long long total = (long long)n_edges * 32;
        int blocks = (int)((total + 255) / 256);
        scatter_add_kernel<26><<<blocks, 256, 0, stream>>>(feat, src, dst, agg1, n_edges);
    }

    node_mlp_kernel<<<(n_nodes + 255) / 256, 256, 0, stream>>>(
        feat, agg1, deg, W1s, W1n, b1, W2s, W2n, b2, out, t2, n_nodes);

    {
        long long total = (long long)n_edges * 32;
        int blocks = (int)((total + 255) / 256);
        scatter_add_kernel<24><<<blocks, 256, 0, stream>>>(t2, src, dst, aggT, n_edges);
    }

    finalize_kernel<<<(n_nodes + 255) / 256, 256, 0, stream>>>(out, aggT, deg, n_nodes);
}

// Round 2
// 1306.514 us; speedup vs baseline: 1.4406x; 1.4406x over previous
//
#include <hip/hip_runtime.h>
#include <math.h>

// GraphSAGE-mean 2-layer, CSR-gather formulation (no float atomics).
// Pipeline: int-histogram(deg) -> exclusive scan -> atomic placement (CSR) ->
//   gather1 (mean of feat over in-neighbors, 26 dims) ->
//   node_mlp (h1 = relu(feat@W1s + mean@W1n + b1); out = h1@W2s+b2; t2 = h1@W2n) ->
//   gather2+finalize (out = log_softmax(out + mean(t2)@identity)).
// Layer-2 trick: aggregate h1@W2_neigh (24 dims) instead of h1 (40) — mean commutes with linear.
// t2 aliases the mean buffer (stride 26, cols 0..23): each row is read before written by the same thread.

typedef long long ll;

__global__ void hist_kernel(const int* __restrict__ dst, int* __restrict__ degi, int n_edges) {
    int i = blockIdx.x * blockDim.x + threadIdx.x;
    int base = i * 4;
    if (base + 3 < n_edges) {
        int4 d = *reinterpret_cast<const int4*>(dst + base);
        atomicAdd(&degi[d.x], 1);
        atomicAdd(&degi[d.y], 1);
        atomicAdd(&degi[d.z], 1);
        atomicAdd(&degi[d.w], 1);
    } else {
        for (int e = base; e < n_edges; e++) atomicAdd(&degi[dst[e]], 1);
    }
}

// Block-level exclusive scan: 256 threads x 8 elems = 2048/block. Writes per-element
// exclusive-within-block prefix to out, block total to bsums.
__global__ void __launch_bounds__(256) scan1_kernel(const int* __restrict__ in, int* __restrict__ out,
                                                    int* __restrict__ bsums, int n) {
    __shared__ int lds[256];
    int t = threadIdx.x;
    int base = blockIdx.x * 2048 + t * 8;
    int v[8];
    int s = 0;
#pragma unroll
    for (int i = 0; i < 8; i++) { v[i] = (base + i < n) ? in[base + i] : 0; s += v[i]; }
    lds[t] = s;
    __syncthreads();
    for (int off = 1; off < 256; off <<= 1) {
        int tv = (t >= off) ? lds[t - off] : 0;
        __syncthreads();
        lds[t] += tv;
        __syncthreads();
    }
    int excl = lds[t] - s;
    if (t == 255) bsums[blockIdx.x] = lds[255];
    int run = excl;
#pragma unroll
    for (int i = 0; i < 8; i++) {
        if (base + i < n) out[base + i] = run;
        run += v[i];
    }
}

// Exclusive scan of block sums (nb <= 256).
__global__ void __launch_bounds__(256) scan2_kernel(int* __restrict__ bsums, int nb) {
    __shared__ int lds[256];
    int t = threadIdx.x;
    int v = (t < nb) ? bsums[t] : 0;
    lds[t] = v;
    __syncthreads();
    for (int off = 1; off < 256; off <<= 1) {
        int tv = (t >= off) ? lds[t - off] : 0;
        __syncthreads();
        lds[t] += tv;
        __syncthreads();
    }
    if (t < nb) bsums[t] = lds[t] - v;
}

__global__ void scan3_kernel(int* __restrict__ out, const int* __restrict__ bsums, int n) {
    int i = blockIdx.x * blockDim.x + threadIdx.x;
    if (i < n) out[i] += bsums[i >> 11];
}

// pos = fetch_add(cursor[dst]); csr[pos] = src. After this, cursor[d] == end offset of d.
__global__ void place_kernel(const int* __restrict__ src, const int* __restrict__ dst,
                             int* __restrict__ cursor, int* __restrict__ csr, int n_edges) {
    int e = blockIdx.x * blockDim.x + threadIdx.x;
    if (e < n_edges) {
        int d = dst[e];
        int pos = atomicAdd(&cursor[d], 1);
        csr[pos] = src[e];
    }
}

// One 32-lane group per node; lane f accumulates feature f over neighbors. Writes MEAN (scaled).
__global__ void __launch_bounds__(256) gather_mean26_kernel(
        const float* __restrict__ feat, const int* __restrict__ csr,
        const int* __restrict__ endoff, const int* __restrict__ degi,
        float* __restrict__ buf, int n_nodes) {
    int g = (blockIdx.x * 256 + threadIdx.x) >> 5;
    int lane = threadIdx.x & 31;
    if (g >= n_nodes) return;
    int end = endoff[g];
    int dg = degi[g];
    int start = end - dg;
    int c = lane < 26 ? lane : 0;
    float acc = 0.0f;
    int k = start;
    while (k < end) {
        int cnt = min(end - k, 32);
        int myid = (k + lane < end) ? csr[k + lane] : 0;
#pragma unroll 4
        for (int j = 0; j < cnt; j++) {
            int s = __shfl(myid, j, 32);
            acc += feat[(ll)s * 26 + c];
        }
        k += cnt;
    }
    float dinv = dg > 0 ? 1.0f / (float)dg : 0.0f;
    if (lane < 26) buf[(ll)g * 26 + lane] = acc * dinv;
}

// Per-node MLP. buf rows: in = mean (26), out (same rows) = t2 = h1@W2n (24, stride 26).
__global__ void __launch_bounds__(256) node_mlp_kernel(
        const float* __restrict__ feat, float* buf,
        const float* __restrict__ W1s, const float* __restrict__ W1n, const float* __restrict__ b1,
        const float* __restrict__ W2s, const float* __restrict__ W2n, const float* __restrict__ b2,
        float* __restrict__ outp, int n_nodes) {
    __shared__ float sW1s[26 * 40];
    __shared__ float sW1n[26 * 40];
    __shared__ float sW2s[40 * 24];
    __shared__ float sW2n[40 * 24];
    __shared__ float sb1[40];
    __shared__ float sb2[24];
    int t = threadIdx.x;
    for (int i = t; i < 26 * 40; i += 256) { sW1s[i] = W1s[i]; sW1n[i] = W1n[i]; }
    for (int i = t; i < 40 * 24; i += 256) { sW2s[i] = W2s[i]; sW2n[i] = W2n[i]; }
    if (t < 40) sb1[t] = b1[t];
    if (t < 24) sb2[t] = b2[t];
    __syncthreads();

    int n = blockIdx.x * 256 + t;
    if (n >= n_nodes) return;

    float h[40];
#pragma unroll
    for (int j = 0; j < 40; j++) h[j] = sb1[j];

    const float* fr = feat + (ll)n * 26;
    float* br = buf + (ll)n * 26;
#pragma unroll
    for (int k = 0; k < 26; k++) {
        float f = fr[k];
        float a = br[k];
#pragma unroll
        for (int j = 0; j < 40; j++) h[j] += f * sW1s[k * 40 + j] + a * sW1n[k * 40 + j];
    }
#pragma unroll
    for (int j = 0; j < 40; j++) h[j] = h[j] > 0.0f ? h[j] : 0.0f;

    float o[24], tt[24];
#pragma unroll
    for (int j = 0; j < 24; j++) { o[j] = sb2[j]; tt[j] = 0.0f; }
#pragma unroll
    for (int k = 0; k < 40; k++) {
        float hv = h[k];
#pragma unroll
        for (int j = 0; j < 24; j++) {
            o[j]  += hv * sW2s[k * 24 + j];
            tt[j] += hv * sW2n[k * 24 + j];
        }
    }
    float* op = outp + (ll)n * 24;
#pragma unroll
    for (int j = 0; j < 24; j++) op[j] = o[j];
#pragma unroll
    for (int j = 0; j < 24; j++) br[j] = tt[j];
}

// One 32-lane group per node: mean of t2 over neighbors (24 dims, stride 26),
// add to out, then log_softmax over the 24 classes via intra-group shuffles.
__global__ void __launch_bounds__(256) gather_fin24_kernel(
        const float* __restrict__ buf, const int* __restrict__ csr,
        const int* __restrict__ endoff, const int* __restrict__ degi,
        float* __restrict__ outp, int n_nodes) {
    int g = (blockIdx.x * 256 + threadIdx.x) >> 5;
    int lane = threadIdx.x & 31;
    if (g >= n_nodes) return;
    int end = endoff[g];
    int dg = degi[g];
    int start = end - dg;
    int c = lane < 24 ? lane : 0;
    float acc = 0.0f;
    int k = start;
    while (k < end) {
        int cnt = min(end - k, 32);
        int myid = (k + lane < end) ? csr[k + lane] : 0;
#pragma unroll 4
        for (int j = 0; j < cnt; j++) {
            int s = __shfl(myid, j, 32);
            acc += buf[(ll)s * 26 + c];
        }
        k += cnt;
    }
    float dinv = dg > 0 ? 1.0f / (float)dg : 0.0f;
    float v = (lane < 24) ? outp[(ll)g * 24 + lane] + acc * dinv : -INFINITY;
    float m = v;
#pragma unroll
    for (int mask = 16; mask >= 1; mask >>= 1) m = fmaxf(m, __shfl_xor(m, mask, 32));
    float ex = (lane < 24) ? expf(v - m) : 0.0f;
    float ssum = ex;
#pragma unroll
    for (int mask = 16; mask >= 1; mask >>= 1) ssum += __shfl_xor(ssum, mask, 32);
    if (lane < 24) outp[(ll)g * 24 + lane] = v - m - logf(ssum);
}

extern "C" void kernel_launch(void* const* d_in, const int* in_sizes, int n_in,
                              void* d_out, int out_size, void* d_ws, size_t ws_size,
                              hipStream_t stream) {
    const float* feat = (const float*)d_in[0];
    const int*   src  = (const int*)d_in[1];
    const int*   dst  = (const int*)d_in[2];
    const float* W1s  = (const float*)d_in[3];
    const float* W1n  = (const float*)d_in[4];
    const float* b1   = (const float*)d_in[5];
    const float* W2s  = (const float*)d_in[6];
    const float* W2n  = (const float*)d_in[7];
    const float* b2   = (const float*)d_in[8];

    int n_nodes = in_sizes[0] / 26;
    int n_edges = in_sizes[1];
    float* out = (float*)d_out;

    // Workspace: degi[N] | offs[N] | bsums[256] | csr[E] | buf[N*26]  (~48 MB)
    int* degi  = (int*)d_ws;
    int* offs  = degi + n_nodes;
    int* bsums = offs + n_nodes;
    int* csr   = bsums + 256;
    float* buf = (float*)(csr + n_edges);

    hipMemsetAsync(degi, 0, sizeof(int) * (size_t)n_nodes, stream);

    {
        int work = (n_edges + 3) / 4;
        hist_kernel<<<(work + 255) / 256, 256, 0, stream>>>(dst, degi, n_edges);
    }

    int scan_blocks = (n_nodes + 2047) / 2048;  // 98 for 200k (<=256 required)
    scan1_kernel<<<scan_blocks, 256, 0, stream>>>(degi, offs, bsums, n_nodes);
    scan2_kernel<<<1, 256, 0, stream>>>(bsums, scan_blocks);
    scan3_kernel<<<(n_nodes + 255) / 256, 256, 0, stream>>>(offs, bsums, n_nodes);

    place_kernel<<<(n_edges + 255) / 256, 256, 0, stream>>>(src, dst, offs, csr, n_edges);

    int gather_blocks = (n_nodes * 32 + 255) / 256;
    gather_mean26_kernel<<<gather_blocks, 256, 0, stream>>>(feat, csr, offs, degi, buf, n_nodes);

    node_mlp_kernel<<<(n_nodes + 255) / 256, 256, 0, stream>>>(
        feat, buf, W1s, W1n, b1, W2s, W2n, b2, out, n_nodes);

    gather_fin24_kernel<<<gather_blocks, 256, 0, stream>>>(buf, csr, offs, degi, out, n_nodes);
}

// Round 3
// 1068.305 us; speedup vs baseline: 1.7619x; 1.2230x over previous
//
#include <hip/hip_runtime.h>
#include <math.h>

// GraphSAGE-mean 2-layer. CSR-gather formulation with dst-bucketed CSR build
// (locality for scattered writes) and float4 gathers on 128B-padded rows.
//
// Fast path pipeline:
//   hist(deg) -> scan(offs) -> snapshot bucket bases -> pad feat to stride 32 ->
//   bin edges into 25 dst-range buckets (LDS multi-split, coalesced writes) ->
//   place2 (bucket-ordered: atomics+writes confined to ~1MB L2-resident region) ->
//   gather1 float4 (mean feat, 26 of 32 cols) -> node_mlp -> gather2 float4 + log_softmax.
// Layer-2 trick: aggregate h1@W2_neigh (24 dims) instead of h1 (40) — mean commutes with linear.

typedef long long ll;

// ---------------- common: histogram + scan ----------------

__global__ void hist_kernel(const int* __restrict__ dst, int* __restrict__ degi, int n_edges) {
    int i = blockIdx.x * blockDim.x + threadIdx.x;
    int base = i * 4;
    if (base + 3 < n_edges) {
        int4 d = *reinterpret_cast<const int4*>(dst + base);
        atomicAdd(&degi[d.x], 1);
        atomicAdd(&degi[d.y], 1);
        atomicAdd(&degi[d.z], 1);
        atomicAdd(&degi[d.w], 1);
    } else {
        for (int e = base; e < n_edges; e++) atomicAdd(&degi[dst[e]], 1);
    }
}

__global__ void __launch_bounds__(256) scan1_kernel(const int* __restrict__ in, int* __restrict__ out,
                                                    int* __restrict__ bsums, int n) {
    __shared__ int lds[256];
    int t = threadIdx.x;
    int base = blockIdx.x * 2048 + t * 8;
    int v[8];
    int s = 0;
#pragma unroll
    for (int i = 0; i < 8; i++) { v[i] = (base + i < n) ? in[base + i] : 0; s += v[i]; }
    lds[t] = s;
    __syncthreads();
    for (int off = 1; off < 256; off <<= 1) {
        int tv = (t >= off) ? lds[t - off] : 0;
        __syncthreads();
        lds[t] += tv;
        __syncthreads();
    }
    int excl = lds[t] - s;
    if (t == 255) bsums[blockIdx.x] = lds[255];
    int run = excl;
#pragma unroll
    for (int i = 0; i < 8; i++) {
        if (base + i < n) out[base + i] = run;
        run += v[i];
    }
}

__global__ void __launch_bounds__(256) scan2_kernel(int* __restrict__ bsums, int nb) {
    __shared__ int lds[256];
    int t = threadIdx.x;
    int v = (t < nb) ? bsums[t] : 0;
    lds[t] = v;
    __syncthreads();
    for (int off = 1; off < 256; off <<= 1) {
        int tv = (t >= off) ? lds[t - off] : 0;
        __syncthreads();
        lds[t] += tv;
        __syncthreads();
    }
    if (t < nb) bsums[t] = lds[t] - v;
}

__global__ void scan3_kernel(int* __restrict__ out, const int* __restrict__ bsums, int n) {
    int i = blockIdx.x * blockDim.x + threadIdx.x;
    if (i < n) out[i] += bsums[i >> 11];
}

// ---------------- fast path: bucketed CSR build ----------------

// bbound[b] = offs[b<<13] (edge-range start of bucket b), bbound[nb] = n_edges; bcur = working cursors.
__global__ void snap_kernel(const int* __restrict__ offs, int* __restrict__ bbound,
                            int* __restrict__ bcur, int n_edges, int nb) {
    int t = threadIdx.x;
    if (t < nb) { int v = offs[t << 13]; bbound[t] = v; bcur[t] = v; }
    if (t == nb) bbound[t] = n_edges;
}

__global__ void pad_feat_kernel(const float* __restrict__ feat, float* __restrict__ featp, int total) {
    int i = blockIdx.x * 256 + threadIdx.x;
    if (i >= total) return;
    int n = i >> 5, c = i & 31;
    featp[i] = (c < 26) ? feat[n * 26 + c] : 0.0f;
}

#define BIN_CHUNK 4096

// LDS multi-split of edges into nb dst-range buckets (node range 8192 each).
// Packs (dst_local<<18)|src into one u32. Output writes are coalesced runs.
__global__ void __launch_bounds__(256) bin_kernel(const int* __restrict__ src, const int* __restrict__ dst,
                                                  int* __restrict__ bcur, unsigned* __restrict__ ebuf,
                                                  int n_edges, int nb) {
    __shared__ int cnt[32];
    __shared__ int run[32];
    __shared__ int loff[33];
    __shared__ int gbase[32];
    __shared__ unsigned stage[BIN_CHUNK];
    int t = threadIdx.x;
    int base = blockIdx.x * BIN_CHUNK;
    if (t < nb) cnt[t] = 0;
    __syncthreads();
#pragma unroll
    for (int j = 0; j < BIN_CHUNK / 256; j++) {
        int i = base + t + j * 256;
        if (i < n_edges) atomicAdd(&cnt[dst[i] >> 13], 1);
    }
    __syncthreads();
    if (t == 0) {
        int s = 0;
        for (int b = 0; b < nb; b++) { loff[b] = s; s += cnt[b]; }
        loff[nb] = s;
    }
    __syncthreads();
    if (t < nb) { gbase[t] = atomicAdd(&bcur[t], cnt[t]); run[t] = loff[t]; }
    __syncthreads();
#pragma unroll
    for (int j = 0; j < BIN_CHUNK / 256; j++) {
        int i = base + t + j * 256;
        if (i < n_edges) {
            int d = dst[i];
            int b = d >> 13;
            unsigned u = ((unsigned)(d - (b << 13)) << 18) | (unsigned)src[i];
            int p = atomicAdd(&run[b], 1);
            stage[p] = u;
        }
    }
    __syncthreads();
    int total = loff[nb];
    for (int i = t; i < total; i += 256) {
        int lo = 0, hi = nb - 1;
        while (lo < hi) { int mid = (lo + hi + 1) >> 1; if (i >= loff[mid]) lo = mid; else hi = mid - 1; }
        ebuf[gbase[lo] + (i - loff[lo])] = stage[i];
    }
}

// Edges arrive bucket-major: active cursor+csr region is small and L2-resident.
__global__ void __launch_bounds__(256) place2_kernel(const unsigned* __restrict__ ebuf,
                                                     const int* __restrict__ bbound,
                                                     int* __restrict__ cursor, int* __restrict__ csr,
                                                     int n_edges, int nb) {
    __shared__ int bb[33];
    int t = threadIdx.x;
    if (t <= nb) bb[t] = bbound[t];
    __syncthreads();
    int i = blockIdx.x * 256 + t;
    if (i >= n_edges) return;
    unsigned u = ebuf[i];
    int lo = 0, hi = nb - 1;
    while (lo < hi) { int mid = (lo + hi + 1) >> 1; if (i >= bb[mid]) lo = mid; else hi = mid - 1; }
    int d = (lo << 13) + (int)(u >> 18);
    int s = (int)(u & 0x3FFFFu);
    int pos = atomicAdd(&cursor[d], 1);
    csr[pos] = s;
}

// ---------------- fast path: float4 gathers (rows padded to 32 floats) ----------------

// One node per 32-lane group. lane = oct*8+q: oct in [0,4) = neighbor slot, q in [0,8) = float4 slot.
// FIN=0: buf[g*32+..] = mean (pads come out 0). FIN=1: out = log_softmax(out + mean) over 24 cols.
template<int FIN>
__global__ void __launch_bounds__(256) gather4_kernel(
        const float* __restrict__ table, const int* __restrict__ csr,
        const int* __restrict__ endoff, const int* __restrict__ degi,
        float* __restrict__ buf, float* __restrict__ outp, int n_nodes) {
    int g = (blockIdx.x * 256 + threadIdx.x) >> 5;
    if (g >= n_nodes) return;
    int lane = threadIdx.x & 31;
    int oct = lane >> 3;
    int q = lane & 7;
    int end = endoff[g];
    int dg = degi[g];
    int start = end - dg;
    float4 acc = make_float4(0.f, 0.f, 0.f, 0.f);
    for (int k = start; k < end; k += 32) {
        int cnt = min(end - k, 32);
        int myid = (lane < cnt) ? csr[k + lane] : 0;
#pragma unroll
        for (int it = 0; it < 8; it++) {
            if ((it << 2) >= cnt) break;
            int nidx = (it << 2) + oct;
            int s = __shfl(myid, nidx, 32);
            if (nidx < cnt) {
                float4 v = *(reinterpret_cast<const float4*>(table + ((ll)s << 5)) + q);
                acc.x += v.x; acc.y += v.y; acc.z += v.z; acc.w += v.w;
            }
        }
    }
#pragma unroll
    for (int m = 8; m <= 16; m <<= 1) {
        acc.x += __shfl_xor(acc.x, m, 32);
        acc.y += __shfl_xor(acc.y, m, 32);
        acc.z += __shfl_xor(acc.z, m, 32);
        acc.w += __shfl_xor(acc.w, m, 32);
    }
    float dinv = dg > 0 ? 1.0f / (float)dg : 0.0f;
    if (FIN == 0) {
        if (lane < 8) {
            float4 r = make_float4(acc.x * dinv, acc.y * dinv, acc.z * dinv, acc.w * dinv);
            *(reinterpret_cast<float4*>(buf + ((ll)g << 5)) + q) = r;
        }
    } else {
        if (lane < 8) {
            float4 v = make_float4(0.f, 0.f, 0.f, 0.f);
            if (q < 6) {
                v = *(reinterpret_cast<float4*>(outp + (ll)g * 24) + q);
                v.x += acc.x * dinv; v.y += acc.y * dinv; v.z += acc.z * dinv; v.w += acc.w * dinv;
            }
            float vm = (q < 6) ? fmaxf(fmaxf(v.x, v.y), fmaxf(v.z, v.w)) : -INFINITY;
#pragma unroll
            for (int m = 1; m <= 4; m <<= 1) vm = fmaxf(vm, __shfl_xor(vm, m, 32));
            float es = (q < 6) ? (expf(v.x - vm) + expf(v.y - vm) + expf(v.z - vm) + expf(v.w - vm)) : 0.0f;
#pragma unroll
            for (int m = 1; m <= 4; m <<= 1) es += __shfl_xor(es, m, 32);
            if (q < 6) {
                float l = vm + logf(es);
                v.x -= l; v.y -= l; v.z -= l; v.w -= l;
                *(reinterpret_cast<float4*>(outp + (ll)g * 24) + q) = v;
            }
        }
    }
}

// ---------------- node MLP (both paths; BSTRIDE = buf row stride, PAD writes zero cols 24..31) ----------------

template<int BSTRIDE, int PAD>
__global__ void __launch_bounds__(256) node_mlp_kernel(
        const float* __restrict__ feat, float* buf,
        const float* __restrict__ W1s, const float* __restrict__ W1n, const float* __restrict__ b1,
        const float* __restrict__ W2s, const float* __restrict__ W2n, const float* __restrict__ b2,
        float* __restrict__ outp, int n_nodes) {
    __shared__ float sW1s[26 * 40];
    __shared__ float sW1n[26 * 40];
    __shared__ float sW2s[40 * 24];
    __shared__ float sW2n[40 * 24];
    __shared__ float sb1[40];
    __shared__ float sb2[24];
    int t = threadIdx.x;
    for (int i = t; i < 26 * 40; i += 256) { sW1s[i] = W1s[i]; sW1n[i] = W1n[i]; }
    for (int i = t; i < 40 * 24; i += 256) { sW2s[i] = W2s[i]; sW2n[i] = W2n[i]; }
    if (t < 40) sb1[t] = b1[t];
    if (t < 24) sb2[t] = b2[t];
    __syncthreads();

    int n = blockIdx.x * 256 + t;
    if (n >= n_nodes) return;

    float h[40];
#pragma unroll
    for (int j = 0; j < 40; j++) h[j] = sb1[j];

    const float* fr = feat + (ll)n * 26;
    float* br = buf + (ll)n * BSTRIDE;
#pragma unroll
    for (int k = 0; k < 26; k++) {
        float f = fr[k];
        float a = br[k];
#pragma unroll
        for (int j = 0; j < 40; j++) h[j] += f * sW1s[k * 40 + j] + a * sW1n[k * 40 + j];
    }
#pragma unroll
    for (int j = 0; j < 40; j++) h[j] = h[j] > 0.0f ? h[j] : 0.0f;

    float o[24], tt[24];
#pragma unroll
    for (int j = 0; j < 24; j++) { o[j] = sb2[j]; tt[j] = 0.0f; }
#pragma unroll
    for (int k = 0; k < 40; k++) {
        float hv = h[k];
#pragma unroll
        for (int j = 0; j < 24; j++) {
            o[j]  += hv * sW2s[k * 24 + j];
            tt[j] += hv * sW2n[k * 24 + j];
        }
    }
    float* op = outp + (ll)n * 24;
#pragma unroll
    for (int j = 0; j < 24; j++) op[j] = o[j];
#pragma unroll
    for (int j = 0; j < 24; j++) br[j] = tt[j];
    if (PAD) {
#pragma unroll
        for (int j = 24; j < 32; j++) br[j] = 0.0f;
    }
}

// ---------------- fallback path kernels (round-2 proven) ----------------

__global__ void place_kernel(const int* __restrict__ src, const int* __restrict__ dst,
                             int* __restrict__ cursor, int* __restrict__ csr, int n_edges) {
    int e = blockIdx.x * blockDim.x + threadIdx.x;
    if (e < n_edges) {
        int d = dst[e];
        int pos = atomicAdd(&cursor[d], 1);
        csr[pos] = src[e];
    }
}

__global__ void __launch_bounds__(256) gather_mean26_kernel(
        const float* __restrict__ feat, const int* __restrict__ csr,
        const int* __restrict__ endoff, const int* __restrict__ degi,
        float* __restrict__ buf, int n_nodes) {
    int g = (blockIdx.x * 256 + threadIdx.x) >> 5;
    int lane = threadIdx.x & 31;
    if (g >= n_nodes) return;
    int end = endoff[g];
    int dg = degi[g];
    int start = end - dg;
    int c = lane < 26 ? lane : 0;
    float acc = 0.0f;
    int k = start;
    while (k < end) {
        int cnt = min(end - k, 32);
        int myid = (k + lane < end) ? csr[k + lane] : 0;
#pragma unroll 4
        for (int j = 0; j < cnt; j++) {
            int s = __shfl(myid, j, 32);
            acc += feat[(ll)s * 26 + c];
        }
        k += cnt;
    }
    float dinv = dg > 0 ? 1.0f / (float)dg : 0.0f;
    if (lane < 26) buf[(ll)g * 26 + lane] = acc * dinv;
}

__global__ void __launch_bounds__(256) gather_fin24_kernel(
        const float* __restrict__ buf, const int* __restrict__ csr,
        const int* __restrict__ endoff, const int* __restrict__ degi,
        float* __restrict__ outp, int n_nodes) {
    int g = (blockIdx.x * 256 + threadIdx.x) >> 5;
    int lane = threadIdx.x & 31;
    if (g >= n_nodes) return;
    int end = endoff[g];
    int dg = degi[g];
    int start = end - dg;
    int c = lane < 24 ? lane : 0;
    float acc = 0.0f;
    int k = start;
    while (k < end) {
        int cnt = min(end - k, 32);
        int myid = (k + lane < end) ? csr[k + lane] : 0;
#pragma unroll 4
        for (int j = 0; j < cnt; j++) {
            int s = __shfl(myid, j, 32);
            acc += buf[(ll)s * 26 + c];
        }
        k += cnt;
    }
    float dinv = dg > 0 ? 1.0f / (float)dg : 0.0f;
    float v = (lane < 24) ? outp[(ll)g * 24 + lane] + acc * dinv : -INFINITY;
    float m = v;
#pragma unroll
    for (int mask = 16; mask >= 1; mask >>= 1) m = fmaxf(m, __shfl_xor(m, mask, 32));
    float ex = (lane < 24) ? expf(v - m) : 0.0f;
    float ssum = ex;
#pragma unroll
    for (int mask = 16; mask >= 1; mask >>= 1) ssum += __shfl_xor(ssum, mask, 32);
    if (lane < 24) outp[(ll)g * 24 + lane] = v - m - logf(ssum);
}

// ---------------- launch ----------------

extern "C" void kernel_launch(void* const* d_in, const int* in_sizes, int n_in,
                              void* d_out, int out_size, void* d_ws, size_t ws_size,
                              hipStream_t stream) {
    const float* feat = (const float*)d_in[0];
    const int*   src  = (const int*)d_in[1];
    const int*   dst  = (const int*)d_in[2];
    const float* W1s  = (const float*)d_in[3];
    const float* W1n  = (const float*)d_in[4];
    const float* b1   = (const float*)d_in[5];
    const float* W2s  = (const float*)d_in[6];
    const float* W2n  = (const float*)d_in[7];
    const float* b2   = (const float*)d_in[8];

    int n_nodes = in_sizes[0] / 26;
    int n_edges = in_sizes[1];
    float* out = (float*)d_out;

    int NB = (n_nodes + 8191) >> 13;  // 25 for 200000

    // fast-path workspace need (elements, each array 16B-aligned)
    size_t off = 0;
    auto alloc = [&off](size_t cnt) { size_t r = off; off += (cnt + 3) & ~(size_t)3; return r; };
    size_t o_degi  = alloc(n_nodes);
    size_t o_offs  = alloc(n_nodes);
    size_t o_bsums = alloc(256);
    size_t o_bb    = alloc(NB + 1);
    size_t o_bcur  = alloc(NB);
    size_t o_csr   = alloc(n_edges);
    size_t o_ebuf  = alloc(n_edges);          // aliased as buf (n_nodes*32 <= n_edges here)
    size_t o_featp = alloc((size_t)n_nodes * 32);
    size_t need = off * 4;

    bool fast = (NB <= 32) && (n_nodes <= (1 << 18)) &&
                ((size_t)n_nodes * 32 <= (size_t)n_edges) && (ws_size >= need);

    int scan_blocks = (n_nodes + 2047) / 2048;

    if (fast) {
        int* base = (int*)d_ws;
        int* degi  = base + o_degi;
        int* offs  = base + o_offs;
        int* bsums = base + o_bsums;
        int* bb    = base + o_bb;
        int* bcur  = base + o_bcur;
        int* csr   = base + o_csr;
        unsigned* ebuf = (unsigned*)(base + o_ebuf);
        float* featp   = (float*)(base + o_featp);
        float* buf     = (float*)ebuf;  // alias: ebuf dead after place2, buf born at gather1

        hipMemsetAsync(degi, 0, sizeof(int) * (size_t)n_nodes, stream);
        {
            int work = (n_edges + 3) / 4;
            hist_kernel<<<(work + 255) / 256, 256, 0, stream>>>(dst, degi, n_edges);
        }
        scan1_kernel<<<scan_blocks, 256, 0, stream>>>(degi, offs, bsums, n_nodes);
        scan2_kernel<<<1, 256, 0, stream>>>(bsums, scan_blocks);
        scan3_kernel<<<(n_nodes + 255) / 256, 256, 0, stream>>>(offs, bsums, n_nodes);

        snap_kernel<<<1, 256, 0, stream>>>(offs, bb, bcur, n_edges, NB);

        {
            int total = n_nodes * 32;
            pad_feat_kernel<<<(total + 255) / 256, 256, 0, stream>>>(feat, featp, total);
        }

        bin_kernel<<<(n_edges + BIN_CHUNK - 1) / BIN_CHUNK, 256, 0, stream>>>(src, dst, bcur, ebuf, n_edges, NB);
        place2_kernel<<<(n_edges + 255) / 256, 256, 0, stream>>>(ebuf, bb, offs, csr, n_edges, NB);

        int gather_blocks = (n_nodes * 32 + 255) / 256;
        gather4_kernel<0><<<gather_blocks, 256, 0, stream>>>(featp, csr, offs, degi, buf, nullptr, n_nodes);

        node_mlp_kernel<32, 1><<<(n_nodes + 255) / 256, 256, 0, stream>>>(
            feat, buf, W1s, W1n, b1, W2s, W2n, b2, out, n_nodes);

        gather4_kernel<1><<<gather_blocks, 256, 0, stream>>>(buf, csr, offs, degi, nullptr, out, n_nodes);
    } else {
        // round-2 proven path (smaller workspace)
        int* degi  = (int*)d_ws;
        int* offs  = degi + n_nodes;
        int* bsums = offs + n_nodes;
        int* csr   = bsums + 256;
        float* buf = (float*)(csr + n_edges);

        hipMemsetAsync(degi, 0, sizeof(int) * (size_t)n_nodes, stream);
        {
            int work = (n_edges + 3) / 4;
            hist_kernel<<<(work + 255) / 256, 256, 0, stream>>>(dst, degi, n_edges);
        }
        scan1_kernel<<<scan_blocks, 256, 0, stream>>>(degi, offs, bsums, n_nodes);
        scan2_kernel<<<1, 256, 0, stream>>>(bsums, scan_blocks);
        scan3_kernel<<<(n_nodes + 255) / 256, 256, 0, stream>>>(offs, bsums, n_nodes);

        place_kernel<<<(n_edges + 255) / 256, 256, 0, stream>>>(src, dst, offs, csr, n_edges);

        int gather_blocks = (n_nodes * 32 + 255) / 256;
        gather_mean26_kernel<<<gather_blocks, 256, 0, stream>>>(feat, csr, offs, degi, buf, n_nodes);

        node_mlp_kernel<26, 0><<<(n_nodes + 255) / 256, 256, 0, stream>>>(
            feat, buf, W1s, W1n, b1, W2s, W2n, b2, out, n_nodes);

        gather_fin24_kernel<<<gather_blocks, 256, 0, stream>>>(buf, csr, offs, degi, out, n_nodes);
    }
}